// Round 9
// baseline (14732.181 us; speedup 1.0000x reference)
//
#include <hip/hip_runtime.h>
#include <cstdint>
#include <cstddef>

#define T_LEN 512
#define S_LEN 512
#define HID   1024
#define AD    256
#define VOC   50257
#define G3    3072
#define NWG   256
#define NT    512
#define NPART (197*4)

// ---------------- workspace layout (float offsets) ----------------
#define WS_GENC   0
#define WS_GITOK  (WS_GENC + G3*S_LEN)          // [512][3072]
#define WS_EX     (WS_GITOK + T_LEN*G3)         // [512][256]
#define WS_H1     (WS_EX + S_LEN*AD)            // [512][1024]
#define WS_FC1    (WS_H1 + T_LEN*HID)           // [512][32]
#define WS_NH0    (WS_FC1 + T_LEN*32)
#define WS_NH1    (WS_NH0 + HID)
#define WS_WB     (WS_NH1 + HID)                 // 512
#define WS_U0     (WS_WB + S_LEN)                // 256
#define WS_U1     (WS_U0 + AD)                   // 256
#define WS_E0P    (WS_U1 + AD)                   // 256
#define WS_E1P    (WS_E0P + 256)                 // 256
#define WS_BARX   (WS_E1P + 256)                 // 256 uint slots (direct-poll barrier)
#define WS_ROWP   (WS_BARX + 64)                 // [512][788]
#define WS_INV    (WS_ROWP + T_LEN*NPART)
#define WS_END    (WS_INV + T_LEN)

__device__ inline float wred64(float v) {
  v += __shfl_xor(v, 32, 64); v += __shfl_xor(v, 16, 64); v += __shfl_xor(v, 8, 64);
  v += __shfl_xor(v, 4, 64);  v += __shfl_xor(v, 2, 64);  v += __shfl_xor(v, 1, 64);
  return v;
}

__device__ inline float fast_sigmoid(float x) { return 1.f / (1.f + __expf(-x)); }
__device__ inline float fast_tanh(float x) {
  float e = __expf(2.f * x);
  return 1.f - 2.f / (e + 1.f);
}

// agent-scope (LLC-coherent) state accessors
__device__ inline float ldw(const float* p) {
  return __uint_as_float(__hip_atomic_load((const unsigned int*)p,
                                           __ATOMIC_RELAXED, __HIP_MEMORY_SCOPE_AGENT));
}
__device__ inline void stw(float* p, float v) {
  __hip_atomic_store((unsigned int*)p, __float_as_uint(v),
                     __ATOMIC_RELAXED, __HIP_MEMORY_SCOPE_AGENT);
}
__device__ inline unsigned ldu(const unsigned* p) {
  return __hip_atomic_load(p, __ATOMIC_RELAXED, __HIP_MEMORY_SCOPE_AGENT);
}

// 2-RT barrier: monotonic per-WG slot, release-store arrival, EVERY WG's wave 0
// polls the whole slot array directly (4 adjacent dwords/lane, coalesced 1KB).
// No checker WG, no gen indirection, no central serialization.
__device__ inline void gbar(unsigned* slot, unsigned b) {
  __syncthreads();   // all waves' loads/stores drained (compiler emits vmcnt(0))
  if (threadIdx.x == 0)
    __hip_atomic_store(slot + blockIdx.x, b, __ATOMIC_RELEASE, __HIP_MEMORY_SCOPE_AGENT);
  if (threadIdx.x < 64) {
    const unsigned* p = slot + (threadIdx.x << 2);
    for (;;) {
      const unsigned a0 = ldu(p), a1 = ldu(p + 1), a2 = ldu(p + 2), a3 = ldu(p + 3);
      if ((a0 >= b) & (a1 >= b) & (a2 >= b) & (a3 >= b)) break;
      __builtin_amdgcn_s_sleep(1);
    }
  }
  __syncthreads();
}

// ---------------- init: zero recurrent state + barrier slots ----------------
__global__ void k_init(float* ws) {
  const int tid = threadIdx.x;
  for (int i = tid; i < HID; i += 256) { ws[WS_NH0 + i] = 0.f; ws[WS_NH1 + i] = 0.f; }
  if (tid < AD) { ws[WS_U0 + tid] = 0.f; ws[WS_U1 + tid] = 0.f; }
  ws[WS_E0P + tid] = 0.f;   // 256
  ws[WS_E1P + tid] = 0.f;   // 256
  ((unsigned*)(ws + WS_BARX))[tid] = 0u;   // 256 slots
}

// ---------------- generic tiled fp32 GEMM (pre/post passes) ----------------
__global__ __launch_bounds__(256) void k_gemm(
    const float* __restrict__ A, int lda, const int* __restrict__ gidx,
    const float* __restrict__ B, int ldb, int kofs,
    const float* __restrict__ bias, float* __restrict__ C, int ldc,
    int M, int N, int act)
{
  __shared__ float As[64][33];
  __shared__ float Bs[64][33];
  const int bm = blockIdx.y * 64, bn = blockIdx.x * 64;
  const int tx = threadIdx.x & 15, ty = threadIdx.x >> 4;
  float acc[4][4] = {};
  const int lin = threadIdx.x * 8;
  const int lr = lin >> 5;
  const int lc = lin & 31;
  for (int k0 = 0; k0 < 1024; k0 += 32) {
    {
      const int gm = bm + lr;
      float4 v0 = {0,0,0,0}, v1 = {0,0,0,0};
      if (gm < M) {
        const int row = gidx ? gidx[gm] : gm;
        const float* p = A + (size_t)row * lda + k0 + lc;
        v0 = *(const float4*)p; v1 = *(const float4*)(p + 4);
      }
      As[lr][lc+0]=v0.x; As[lr][lc+1]=v0.y; As[lr][lc+2]=v0.z; As[lr][lc+3]=v0.w;
      As[lr][lc+4]=v1.x; As[lr][lc+5]=v1.y; As[lr][lc+6]=v1.z; As[lr][lc+7]=v1.w;
    }
    {
      const int gn = bn + lr;
      float4 v0 = {0,0,0,0}, v1 = {0,0,0,0};
      if (gn < N) {
        const float* p = B + (size_t)gn * ldb + kofs + k0 + lc;
        v0 = *(const float4*)p; v1 = *(const float4*)(p + 4);
      }
      Bs[lr][lc+0]=v0.x; Bs[lr][lc+1]=v0.y; Bs[lr][lc+2]=v0.z; Bs[lr][lc+3]=v0.w;
      Bs[lr][lc+4]=v1.x; Bs[lr][lc+5]=v1.y; Bs[lr][lc+6]=v1.z; Bs[lr][lc+7]=v1.w;
    }
    __syncthreads();
    #pragma unroll
    for (int kk = 0; kk < 32; ++kk) {
      float a0 = As[ty*4+0][kk], a1 = As[ty*4+1][kk], a2 = As[ty*4+2][kk], a3 = As[ty*4+3][kk];
      float b0 = Bs[tx*4+0][kk], b1 = Bs[tx*4+1][kk], b2 = Bs[tx*4+2][kk], b3 = Bs[tx*4+3][kk];
      acc[0][0]=fmaf(a0,b0,acc[0][0]); acc[0][1]=fmaf(a0,b1,acc[0][1]); acc[0][2]=fmaf(a0,b2,acc[0][2]); acc[0][3]=fmaf(a0,b3,acc[0][3]);
      acc[1][0]=fmaf(a1,b0,acc[1][0]); acc[1][1]=fmaf(a1,b1,acc[1][1]); acc[1][2]=fmaf(a1,b2,acc[1][2]); acc[1][3]=fmaf(a1,b3,acc[1][3]);
      acc[2][0]=fmaf(a2,b0,acc[2][0]); acc[2][1]=fmaf(a2,b1,acc[2][1]); acc[2][2]=fmaf(a2,b2,acc[2][2]); acc[2][3]=fmaf(a2,b3,acc[2][3]);
      acc[3][0]=fmaf(a3,b0,acc[3][0]); acc[3][1]=fmaf(a3,b1,acc[3][1]); acc[3][2]=fmaf(a3,b2,acc[3][2]); acc[3][3]=fmaf(a3,b3,acc[3][3]);
    }
    __syncthreads();
  }
  #pragma unroll
  for (int i = 0; i < 4; ++i)
    #pragma unroll
    for (int j = 0; j < 4; ++j) {
      const int m = bm + ty*4 + i, n = bn + tx*4 + j;
      if (m < M && n < N) {
        float v = acc[i][j] + (bias ? bias[n] : 0.f);
        if (act == 1) v = fmaxf(v, 0.f);
        C[(size_t)m * ldc + n] = v;
      }
    }
}

// ---------------- persistent recurrence: 256 WGs x 512 thr, register-resident weights ----------------
// WG wg owns j-columns [4wg, 4wg+4) -> 12 gate-rows {part*1024 + j} of Whh0/Wih1/Whh1/Genc.
// waves 0..5: 2 gate-rows each. wave 6: Wh row wg (e0/e1) + attn-w row 2wg.
// wave 7: Wac row wg (u0/u1) + attn-w row 2wg+1.
__global__ __launch_bounds__(NT) void k_recur(
    float* __restrict__ ws,
    const float* __restrict__ Whh0, const float* __restrict__ bhh0,
    const float* __restrict__ Wih1, const float* __restrict__ bih1,
    const float* __restrict__ Whh1, const float* __restrict__ bhh1,
    const float* __restrict__ Wh,   const float* __restrict__ bh,
    const float* __restrict__ vh,   const float* __restrict__ vhb,
    const float* __restrict__ va,   const float* __restrict__ vab,
    const float* __restrict__ Wac)
{
  const float* Genc  = ws + WS_GENC;
  const float* gitok = ws + WS_GITOK;
  const float* Ex    = ws + WS_EX;
  float* H1    = ws + WS_H1;
  float* nh0g  = ws + WS_NH0;
  float* nh1g  = ws + WS_NH1;
  float* wbufg = ws + WS_WB;
  float* u0g   = ws + WS_U0;
  float* u1g   = ws + WS_U1;
  float* e0pg  = ws + WS_E0P;
  float* e1pg  = ws + WS_E1P;
  unsigned* slot = (unsigned*)(ws + WS_BARX);

  const int wg = blockIdx.x, tid = threadIdx.x;
  const int lane = tid & 63, wv = tid >> 6;

  __shared__ float xv[HID];      // staged state vector (h0n / nh0 / nh1)
  __shared__ float wl[S_LEN];    // staged attention weights
  __shared__ float cb[AD];       // c = Wa_c @ h0n
  __shared__ float sgit[12], sgh0[12], gh1l[12], sb0[12], sbh1[12], sacc[12];
  __shared__ float sred[8], sal[2], ssc[1];

  // ---- persistent register-resident weights ----
  float4 wreg[28];
  if (wv < 6) {
    #pragma unroll
    for (int r = 0; r < 2; ++r) {
      const int lr = 2 * wv + r;
      const int g = (lr >> 2) * HID + wg * 4 + (lr & 3);
      const float4* p0 = (const float4*)(Whh0 + (size_t)g * HID);
      const float4* p1 = (const float4*)(Wih1 + (size_t)g * HID);
      const float4* p2 = (const float4*)(Whh1 + (size_t)g * HID);
      const float4* pg = (const float4*)(Genc + (size_t)g * S_LEN);
      #pragma unroll
      for (int p = 0; p < 4; ++p) {
        wreg[r*4+p]      = p0[p*64 + lane];
        wreg[8 + r*4+p]  = p1[p*64 + lane];
        wreg[16 + r*4+p] = p2[p*64 + lane];
      }
      #pragma unroll
      for (int p = 0; p < 2; ++p) wreg[24 + r*2+p] = pg[p*64 + lane];
    }
  } else {
    const float* Wrow = (wv == 6) ? (Wh + (size_t)wg * HID) : (Wac + (size_t)wg * HID);
    const float4* p0 = (const float4*)Wrow;
    #pragma unroll
    for (int p = 0; p < 4; ++p) wreg[p] = p0[p*64 + lane];
    const int s = 2 * wg + (wv - 6);
    wreg[4] = ((const float4*)(Ex + (size_t)s * AD))[lane];
    wreg[5] = ((const float4*)va)[lane];
  }

  // combiner biases (threads 0..3, jl = tid)
  float i1r = 0.f, i1z = 0.f, i1n = 0.f;
  if (tid < 4) {
    const int j = wg * 4 + tid;
    i1r = bih1[j]; i1z = bih1[HID + j]; i1n = bih1[2 * HID + j];
  }
  if (tid < 12) {
    const int g = (tid >> 2) * HID + wg * 4 + (tid & 3);
    sb0[tid] = bhh0[g];
    const float bb = bhh1[g];
    sbh1[tid] = bb;
    gh1l[tid] = bb;          // gh1(t=0) = Whh1@0 + bhh1
  }
  const float vhW = vh[wg], bhW = bh[wg];
  const float vabv = vab[0], vhb0 = vhb[0];
  unsigned b = 0;
  __syncthreads();

  const float4* XV4 = (const float4*)xv;
  const float4* WL4 = (const float4*)wl;
  const float4* CB4 = (const float4*)cb;

  #pragma unroll 1
  for (int t = 0; t < T_LEN; ++t) {
    // ========== S1: alpha; gh0 = Whh0 @ h0n + bhh0 ; attention weights w ==========
    {
      // issue all cross-WG state loads up front
      const float a0 = ldw(nh0g + tid), a1 = ldw(nh0g + 512 + tid);
      const float b0 = ldw(nh1g + tid), b1 = ldw(nh1g + 512 + tid);
      float uu0 = 0.f, uu1 = 0.f;
      if (tid < AD) { uu0 = ldw(u0g + tid); uu1 = ldw(u1g + tid); }
      float ep = (tid < 256) ? ldw(e0pg + tid) : ldw(e1pg + tid - 256);
      if (tid < 12)
        sgit[tid] = gitok[(size_t)t * G3 + (tid >> 2) * HID + wg * 4 + (tid & 3)];
      ep = wred64(ep);
      if (lane == 0) sred[wv] = ep;
      __syncthreads();
      if (tid == 0) {
        const float e0 = sred[0] + sred[1] + sred[2] + sred[3] + vhb0;
        const float e1 = sred[4] + sred[5] + sred[6] + sred[7] + vhb0;
        const float ea = __expf(e0), eb = __expf(e1);
        const float s = ea + eb;
        sal[0] = ea / s; sal[1] = eb / s;
      }
      __syncthreads();
      const float al0 = sal[0], al1 = sal[1];
      xv[tid]       = al0 * a0 + al1 * b0;
      xv[tid + 512] = al0 * a1 + al1 * b1;
      if (tid < AD) cb[tid] = al0 * uu0 + al1 * uu1;
      __syncthreads();
      if (wv < 6) {
        const float4 x0 = XV4[lane], x1 = XV4[64+lane], x2 = XV4[128+lane], x3 = XV4[192+lane];
        float accA = 0.f, accB = 0.f;
        #pragma unroll
        for (int p = 0; p < 4; ++p) {
          const float4 xp = (p==0)?x0:((p==1)?x1:((p==2)?x2:x3));
          accA = fmaf(wreg[p].x, xp.x, accA); accA = fmaf(wreg[p].y, xp.y, accA);
          accA = fmaf(wreg[p].z, xp.z, accA); accA = fmaf(wreg[p].w, xp.w, accA);
          accB = fmaf(wreg[4+p].x, xp.x, accB); accB = fmaf(wreg[4+p].y, xp.y, accB);
          accB = fmaf(wreg[4+p].z, xp.z, accB); accB = fmaf(wreg[4+p].w, xp.w, accB);
        }
        accA = wred64(accA); accB = wred64(accB);
        if (lane == 0) {
          sgh0[2*wv]     = accA + sb0[2*wv];
          sgh0[2*wv + 1] = accB + sb0[2*wv + 1];
        }
      } else {
        const float4 e4 = wreg[4], v4 = wreg[5], c4 = CB4[lane];
        const float s0 = fast_tanh(e4.x + c4.x);
        const float s1 = fast_tanh(e4.y + c4.y);
        const float s2 = fast_tanh(e4.z + c4.z);
        const float s3 = fast_tanh(e4.w + c4.w);
        float acc = v4.x*s0 + v4.y*s1 + v4.z*s2 + v4.w*s3;
        acc = wred64(acc);
        if (lane == 0) stw(wbufg + 2*wg + (wv - 6), __expf(acc + vabv));
      }
    }
    gbar(slot, ++b);

    // ========== S2: nh0 = GRU0((Genc @ w)/sum + gi_tok[t], gh0, h0n) ==========
    {
      const float wval = ldw(wbufg + tid);
      wl[tid] = wval;
      const float ps = wred64(wval);
      if (lane == 0) sred[wv] = ps;
      __syncthreads();
      if (tid == 0) {
        float s = 0.f;
        #pragma unroll
        for (int i = 0; i < 8; ++i) s += sred[i];
        ssc[0] = 1.f / s;
      }
      if (wv < 6) {
        const float4 w0 = WL4[lane], w1 = WL4[64 + lane];
        float accA = 0.f, accB = 0.f;
        accA = fmaf(wreg[24].x, w0.x, accA); accA = fmaf(wreg[24].y, w0.y, accA);
        accA = fmaf(wreg[24].z, w0.z, accA); accA = fmaf(wreg[24].w, w0.w, accA);
        accA = fmaf(wreg[25].x, w1.x, accA); accA = fmaf(wreg[25].y, w1.y, accA);
        accA = fmaf(wreg[25].z, w1.z, accA); accA = fmaf(wreg[25].w, w1.w, accA);
        accB = fmaf(wreg[26].x, w0.x, accB); accB = fmaf(wreg[26].y, w0.y, accB);
        accB = fmaf(wreg[26].z, w0.z, accB); accB = fmaf(wreg[26].w, w0.w, accB);
        accB = fmaf(wreg[27].x, w1.x, accB); accB = fmaf(wreg[27].y, w1.y, accB);
        accB = fmaf(wreg[27].z, w1.z, accB); accB = fmaf(wreg[27].w, w1.w, accB);
        accA = wred64(accA); accB = wred64(accB);
        if (lane == 0) { sacc[2*wv] = accA; sacc[2*wv + 1] = accB; }
      }
      __syncthreads();
      if (tid < 4) {
        const float inv = ssc[0];
        const float d0 = sacc[tid]     * inv + sgit[tid];
        const float d1 = sacc[4 + tid] * inv + sgit[4 + tid];
        const float d2 = sacc[8 + tid] * inv + sgit[8 + tid];
        const float rg = fast_sigmoid(d0 + sgh0[tid]);
        const float zg = fast_sigmoid(d1 + sgh0[4 + tid]);
        const float ng = fast_tanh(d2 + rg * sgh0[8 + tid]);
        const float h0j = xv[wg * 4 + tid];
        stw(nh0g + wg * 4 + tid, (1.f - zg) * ng + zg * h0j);
      }
    }
    gbar(slot, ++b);

    // ========== S3: nh1 = GRU1(Wih1@nh0, gh1_prev, nh1_prev); e0, u0 ==========
    {
      const float x0 = ldw(nh0g + tid), x1 = ldw(nh0g + 512 + tid);
      const float oldn = (tid < 4) ? ldw(nh1g + wg * 4 + tid) : 0.f;
      xv[tid] = x0; xv[tid + 512] = x1;
      __syncthreads();
      const float4 y0 = XV4[lane], y1 = XV4[64+lane], y2 = XV4[128+lane], y3 = XV4[192+lane];
      if (wv < 6) {
        float accA = 0.f, accB = 0.f;
        #pragma unroll
        for (int p = 0; p < 4; ++p) {
          const float4 yp = (p==0)?y0:((p==1)?y1:((p==2)?y2:y3));
          accA = fmaf(wreg[8+p].x, yp.x, accA);  accA = fmaf(wreg[8+p].y, yp.y, accA);
          accA = fmaf(wreg[8+p].z, yp.z, accA);  accA = fmaf(wreg[8+p].w, yp.w, accA);
          accB = fmaf(wreg[12+p].x, yp.x, accB); accB = fmaf(wreg[12+p].y, yp.y, accB);
          accB = fmaf(wreg[12+p].z, yp.z, accB); accB = fmaf(wreg[12+p].w, yp.w, accB);
        }
        accA = wred64(accA); accB = wred64(accB);
        if (lane == 0) { sacc[2*wv] = accA; sacc[2*wv + 1] = accB; }
      } else {
        float acc = 0.f;
        #pragma unroll
        for (int p = 0; p < 4; ++p) {
          const float4 yp = (p==0)?y0:((p==1)?y1:((p==2)?y2:y3));
          acc = fmaf(wreg[p].x, yp.x, acc); acc = fmaf(wreg[p].y, yp.y, acc);
          acc = fmaf(wreg[p].z, yp.z, acc); acc = fmaf(wreg[p].w, yp.w, acc);
        }
        acc = wred64(acc);
        if (lane == 0) {
          if (wv == 6) stw(e0pg + wg, vhW * fast_tanh(acc + bhW));
          else         stw(u0g + wg, acc);
        }
      }
      __syncthreads();
      if (tid < 4) {
        const float gr = sacc[tid]     + i1r;
        const float gz = sacc[4 + tid] + i1z;
        const float gn = sacc[8 + tid] + i1n;
        const float rg = fast_sigmoid(gr + gh1l[tid]);
        const float zg = fast_sigmoid(gz + gh1l[4 + tid]);
        const float ng = fast_tanh(gn + rg * gh1l[8 + tid]);
        const float nv = (1.f - zg) * ng + zg * oldn;
        stw(nh1g + wg * 4 + tid, nv);
        H1[(size_t)t * HID + wg * 4 + tid] = nv;
      }
    }
    gbar(slot, ++b);

    // ========== S4: gh1_next = Whh1 @ nh1 + bhh1 ; e1, u1 ==========
    {
      const float x0 = ldw(nh1g + tid), x1 = ldw(nh1g + 512 + tid);
      xv[tid] = x0; xv[tid + 512] = x1;
      __syncthreads();
      const float4 y0 = XV4[lane], y1 = XV4[64+lane], y2 = XV4[128+lane], y3 = XV4[192+lane];
      if (wv < 6) {
        float accA = 0.f, accB = 0.f;
        #pragma unroll
        for (int p = 0; p < 4; ++p) {
          const float4 yp = (p==0)?y0:((p==1)?y1:((p==2)?y2:y3));
          accA = fmaf(wreg[16+p].x, yp.x, accA); accA = fmaf(wreg[16+p].y, yp.y, accA);
          accA = fmaf(wreg[16+p].z, yp.z, accA); accA = fmaf(wreg[16+p].w, yp.w, accA);
          accB = fmaf(wreg[20+p].x, yp.x, accB); accB = fmaf(wreg[20+p].y, yp.y, accB);
          accB = fmaf(wreg[20+p].z, yp.z, accB); accB = fmaf(wreg[20+p].w, yp.w, accB);
        }
        accA = wred64(accA); accB = wred64(accB);
        if (lane == 0) {
          gh1l[2*wv]     = accA + sbh1[2*wv];
          gh1l[2*wv + 1] = accB + sbh1[2*wv + 1];
        }
      } else {
        float acc = 0.f;
        #pragma unroll
        for (int p = 0; p < 4; ++p) {
          const float4 yp = (p==0)?y0:((p==1)?y1:((p==2)?y2:y3));
          acc = fmaf(wreg[p].x, yp.x, acc); acc = fmaf(wreg[p].y, yp.y, acc);
          acc = fmaf(wreg[p].z, yp.z, acc); acc = fmaf(wreg[p].w, yp.w, acc);
        }
        acc = wred64(acc);
        if (lane == 0) {
          if (wv == 6) stw(e1pg + wg, vhW * fast_tanh(acc + bhW));
          else         stw(u1g + wg, acc);
        }
      }
    }
    gbar(slot, ++b);
  }
}

// ---------------- output head: logits -> exp -> per-wave row partials ----------------
__global__ __launch_bounds__(256) void k_head(
    const float* __restrict__ FC1, const float* __restrict__ Wf2,
    const float* __restrict__ bf2, float* __restrict__ out, float* __restrict__ rowp)
{
  __shared__ float fcb[256 * 32];
  const int v = blockIdx.x * 256 + threadIdx.x;
  const bool ok = v < VOC;
  float wf[32];
  float bb = 0.f;
  if (ok) {
    const float4* W4 = (const float4*)(Wf2 + (size_t)v * 32);
    #pragma unroll
    for (int q = 0; q < 8; ++q) ((float4*)wf)[q] = W4[q];
    bb = bf2[v];
  }
  const int wv = threadIdx.x >> 6;
  #pragma unroll 1
  for (int half = 0; half < 2; ++half) {
    __syncthreads();
    for (int i = threadIdx.x; i < 256 * 32 / 4; i += 256)
      ((float4*)fcb)[i] = ((const float4*)(FC1 + half * 256 * 32))[i];
    __syncthreads();
    #pragma unroll 1
    for (int tt = 0; tt < 256; ++tt) {
      const int t = half * 256 + tt;
      const float4* f4 = (const float4*)(fcb + tt * 32);
      float acc = bb;
      #pragma unroll
      for (int q = 0; q < 8; ++q) {
        float4 f = f4[q];
        acc = fmaf(wf[4*q+0], f.x, acc);
        acc = fmaf(wf[4*q+1], f.y, acc);
        acc = fmaf(wf[4*q+2], f.z, acc);
        acc = fmaf(wf[4*q+3], f.w, acc);
      }
      const float w = ok ? __expf(acc) : 0.f;
      if (ok) out[(size_t)t * VOC + v] = w;
      float r = wred64(w);
      if ((threadIdx.x & 63) == 0)
        rowp[(size_t)t * NPART + (size_t)blockIdx.x * 4 + wv] = r;
    }
  }
}

__global__ __launch_bounds__(256) void k_rowsum(const float* __restrict__ rowp, float* __restrict__ inv) {
  const int t = blockIdx.x;
  float acc = 0.f;
  for (int i = threadIdx.x; i < NPART; i += 256) acc += rowp[(size_t)t * NPART + i];
  acc = wred64(acc);
  __shared__ float sr[4];
  if ((threadIdx.x & 63) == 0) sr[threadIdx.x >> 6] = acc;
  __syncthreads();
  if (threadIdx.x == 0) inv[t] = 1.f / (sr[0] + sr[1] + sr[2] + sr[3]);
}

__global__ __launch_bounds__(256) void k_scale(float* __restrict__ out, const float* __restrict__ inv) {
  const int t = blockIdx.y;
  const float s = inv[t];
  const size_t base = (size_t)t * VOC;
  const int v0 = blockIdx.x * 2048 + threadIdx.x;
  #pragma unroll
  for (int k = 0; k < 8; ++k) {
    const int v = v0 + k * 256;
    if (v < VOC) out[base + v] *= s;
  }
}

extern "C" void kernel_launch(void* const* d_in, const int* in_sizes, int n_in,
                              void* d_out, int out_size, void* d_ws, size_t ws_size,
                              hipStream_t stream) {
  const int*   dec  = (const int*)  d_in[0];
  const float* enc  = (const float*)d_in[1];
  const float* emb  = (const float*)d_in[2];
  const float* Wax  = (const float*)d_in[3];
  const float* Wac  = (const float*)d_in[4];
  const float* ba   = (const float*)d_in[5];
  const float* va   = (const float*)d_in[6];
  const float* vab  = (const float*)d_in[7];
  const float* Wih0 = (const float*)d_in[8];
  const float* bih0 = (const float*)d_in[9];
  const float* Whh0 = (const float*)d_in[10];
  const float* bhh0 = (const float*)d_in[11];
  const float* Wih1 = (const float*)d_in[12];
  const float* bih1 = (const float*)d_in[13];
  const float* Whh1 = (const float*)d_in[14];
  const float* bhh1 = (const float*)d_in[15];
  const float* Wh   = (const float*)d_in[16];
  const float* bh   = (const float*)d_in[17];
  const float* vh   = (const float*)d_in[18];
  const float* vhb  = (const float*)d_in[19];
  const float* Wf1  = (const float*)d_in[20];
  const float* bf1  = (const float*)d_in[21];
  const float* Wf2  = (const float*)d_in[22];
  const float* bf2  = (const float*)d_in[23];
  float* out = (float*)d_out;
  float* ws  = (float*)d_ws;

  k_init<<<1, 256, 0, stream>>>(ws);

  // Genc[r][s] = Wih0[r, :1024] . enc[s]          (M=3072, N=512)
  k_gemm<<<dim3(8, 48), 256, 0, stream>>>(Wih0, 2048, nullptr, enc, 1024, 0,
                                          nullptr, ws + WS_GENC, 512, G3, S_LEN, 0);
  // gi_tok[t][r] = emb[dec[t]] . Wih0[r, 1024:] + bih0[r]   (M=512, N=3072)
  k_gemm<<<dim3(48, 8), 256, 0, stream>>>(emb, 1024, dec, Wih0, 2048, 1024,
                                          bih0, ws + WS_GITOK, G3, T_LEN, G3, 0);
  // Ex[s][i] = enc[s] . Wa_x[i] + ba[i]           (M=512, N=256)
  k_gemm<<<dim3(4, 8), 256, 0, stream>>>(enc, 1024, nullptr, Wax, 1024, 0,
                                         ba, ws + WS_EX, AD, S_LEN, AD, 0);

  k_recur<<<NWG, NT, 0, stream>>>(ws, Whh0, bhh0, Wih1, bih1, Whh1, bhh1,
                                  Wh, bh, vh, vhb, va, vab, Wac);

  // FC1[t] = relu(Wf1 @ H1[t] + bf1)              (M=512, N=32)
  k_gemm<<<dim3(1, 8), 256, 0, stream>>>(ws + WS_H1, 1024, nullptr, Wf1, 1024, 0,
                                         bf1, ws + WS_FC1, 32, T_LEN, 32, 1);

  k_head<<<197, 256, 0, stream>>>(ws + WS_FC1, Wf2, bf2, out, ws + WS_ROWP);
  k_rowsum<<<512, 256, 0, stream>>>(ws + WS_ROWP, ws + WS_INV);
  k_scale<<<dim3(25, 512), 256, 0, stream>>>(out, ws + WS_INV);
}

// Round 10
// 11924.168 us; speedup vs baseline: 1.2355x; 1.2355x over previous
//
#include <hip/hip_runtime.h>
#include <cstdint>
#include <cstddef>

#define T_LEN 512
#define S_LEN 512
#define HID   1024
#define AD    256
#define VOC   50257
#define G3    3072
#define NWG   256
#define NT    512
#define NPART (197*4)

// ---------------- workspace layout (float offsets) ----------------
#define WS_GENC   0
#define WS_GITOK  (WS_GENC + G3*S_LEN)          // [512][3072]
#define WS_EX     (WS_GITOK + T_LEN*G3)         // [512][256]
#define WS_H1     (WS_EX + S_LEN*AD)            // [512][1024]
#define WS_FC1    (WS_H1 + T_LEN*HID)           // [512][32]
#define WS_NH0    (WS_FC1 + T_LEN*32)
#define WS_NH1    (WS_NH0 + HID)
#define WS_WB     (WS_NH1 + HID)                 // 512
#define WS_U0     (WS_WB + S_LEN)                // 256
#define WS_U1     (WS_U0 + AD)                   // 256
#define WS_E0P    (WS_U1 + AD)                   // 256
#define WS_E1P    (WS_E0P + 256)                 // 256
#define WS_BARX   (WS_E1P + 256)                 // 512 uints: 256 slots + 8 xa(x16) + 8 gen(x16)
#define WS_ROWP   (WS_BARX + 128)                // [512][788]
#define WS_INV    (WS_ROWP + T_LEN*NPART)
#define WS_END    (WS_INV + T_LEN)

__device__ inline float wred64(float v) {
  v += __shfl_xor(v, 32, 64); v += __shfl_xor(v, 16, 64); v += __shfl_xor(v, 8, 64);
  v += __shfl_xor(v, 4, 64);  v += __shfl_xor(v, 2, 64);  v += __shfl_xor(v, 1, 64);
  return v;
}

__device__ inline float fast_sigmoid(float x) { return 1.f / (1.f + __expf(-x)); }
__device__ inline float fast_tanh(float x) {
  float e = __expf(2.f * x);
  return 1.f - 2.f / (e + 1.f);
}

// agent-scope (LLC-coherent) state accessors
__device__ inline float ldw(const float* p) {
  return __uint_as_float(__hip_atomic_load((const unsigned int*)p,
                                           __ATOMIC_RELAXED, __HIP_MEMORY_SCOPE_AGENT));
}
__device__ inline void stw(float* p, float v) {
  __hip_atomic_store((unsigned int*)p, __float_as_uint(v),
                     __ATOMIC_RELAXED, __HIP_MEMORY_SCOPE_AGENT);
}
__device__ inline unsigned ldu(const unsigned* p) {
  return __hip_atomic_load(p, __ATOMIC_RELAXED, __HIP_MEMORY_SCOPE_AGENT);
}
__device__ inline void stu_rel(unsigned* p, unsigned v) {
  __hip_atomic_store(p, v, __ATOMIC_RELEASE, __HIP_MEMORY_SCOPE_AGENT);
}

// Hierarchical barrier. Group g = wg&7 (XCD-round-robin heuristic; correctness
// independent of mapping). slots[g*32 + (wg>>3)] <- b (release). Leader wg==g
// polls its 32 group slots (2 lines), posts xa[g] (own line), polls all 8 xa,
// posts gen[g] (own line, single writer). Members poll their group's gen.
// Monotonic counters, no reset; every poll set is tiny and single-writer-per-line.
__device__ inline void gbar(unsigned* bar, int wg, unsigned b) {
  unsigned* slots = bar;
  unsigned* xa    = bar + 256;
  unsigned* geng  = bar + 384;
  const int g = wg & 7;
  __syncthreads();   // drains all waves' prior agent-scope stores (vmcnt(0))
  if (threadIdx.x == 0) stu_rel(slots + g * 32 + (wg >> 3), b);
  if (wg < 8) {          // leader of group g == wg
    if (threadIdx.x < 32) {
      const unsigned* p = slots + wg * 32 + threadIdx.x;
      while (ldu(p) < b) __builtin_amdgcn_s_sleep(1);
    }
    __syncthreads();
    if (threadIdx.x == 0) stu_rel(xa + wg * 16, b);
    if (threadIdx.x < 8) {
      const unsigned* p = xa + threadIdx.x * 16;
      while (ldu(p) < b) __builtin_amdgcn_s_sleep(1);
    }
    __syncthreads();
    if (threadIdx.x == 0) stu_rel(geng + wg * 16, b);
  } else {
    if (threadIdx.x == 0) {
      const unsigned* p = geng + g * 16;
      while (ldu(p) < b) __builtin_amdgcn_s_sleep(1);
    }
  }
  __syncthreads();
}

// ---------------- init: zero recurrent state + barrier words ----------------
__global__ void k_init(float* ws) {
  const int tid = threadIdx.x;
  for (int i = tid; i < HID; i += 256) { ws[WS_NH0 + i] = 0.f; ws[WS_NH1 + i] = 0.f; }
  if (tid < AD) { ws[WS_U0 + tid] = 0.f; ws[WS_U1 + tid] = 0.f; }
  ws[WS_E0P + tid] = 0.f;
  ws[WS_E1P + tid] = 0.f;
  for (int i = tid; i < 512; i += 256) ((unsigned*)(ws + WS_BARX))[i] = 0u;
}

// ---------------- generic tiled fp32 GEMM (pre/post passes) ----------------
__global__ __launch_bounds__(256) void k_gemm(
    const float* __restrict__ A, int lda, const int* __restrict__ gidx,
    const float* __restrict__ B, int ldb, int kofs,
    const float* __restrict__ bias, float* __restrict__ C, int ldc,
    int M, int N, int act)
{
  __shared__ float As[64][33];
  __shared__ float Bs[64][33];
  const int bm = blockIdx.y * 64, bn = blockIdx.x * 64;
  const int tx = threadIdx.x & 15, ty = threadIdx.x >> 4;
  float acc[4][4] = {};
  const int lin = threadIdx.x * 8;
  const int lr = lin >> 5;
  const int lc = lin & 31;
  for (int k0 = 0; k0 < 1024; k0 += 32) {
    {
      const int gm = bm + lr;
      float4 v0 = {0,0,0,0}, v1 = {0,0,0,0};
      if (gm < M) {
        const int row = gidx ? gidx[gm] : gm;
        const float* p = A + (size_t)row * lda + k0 + lc;
        v0 = *(const float4*)p; v1 = *(const float4*)(p + 4);
      }
      As[lr][lc+0]=v0.x; As[lr][lc+1]=v0.y; As[lr][lc+2]=v0.z; As[lr][lc+3]=v0.w;
      As[lr][lc+4]=v1.x; As[lr][lc+5]=v1.y; As[lr][lc+6]=v1.z; As[lr][lc+7]=v1.w;
    }
    {
      const int gn = bn + lr;
      float4 v0 = {0,0,0,0}, v1 = {0,0,0,0};
      if (gn < N) {
        const float* p = B + (size_t)gn * ldb + kofs + k0 + lc;
        v0 = *(const float4*)p; v1 = *(const float4*)(p + 4);
      }
      Bs[lr][lc+0]=v0.x; Bs[lr][lc+1]=v0.y; Bs[lr][lc+2]=v0.z; Bs[lr][lc+3]=v0.w;
      Bs[lr][lc+4]=v1.x; Bs[lr][lc+5]=v1.y; Bs[lr][lc+6]=v1.z; Bs[lr][lc+7]=v1.w;
    }
    __syncthreads();
    #pragma unroll
    for (int kk = 0; kk < 32; ++kk) {
      float a0 = As[ty*4+0][kk], a1 = As[ty*4+1][kk], a2 = As[ty*4+2][kk], a3 = As[ty*4+3][kk];
      float b0 = Bs[tx*4+0][kk], b1 = Bs[tx*4+1][kk], b2 = Bs[tx*4+2][kk], b3 = Bs[tx*4+3][kk];
      acc[0][0]=fmaf(a0,b0,acc[0][0]); acc[0][1]=fmaf(a0,b1,acc[0][1]); acc[0][2]=fmaf(a0,b2,acc[0][2]); acc[0][3]=fmaf(a0,b3,acc[0][3]);
      acc[1][0]=fmaf(a1,b0,acc[1][0]); acc[1][1]=fmaf(a1,b1,acc[1][1]); acc[1][2]=fmaf(a1,b2,acc[1][2]); acc[1][3]=fmaf(a1,b3,acc[1][3]);
      acc[2][0]=fmaf(a2,b0,acc[2][0]); acc[2][1]=fmaf(a2,b1,acc[2][1]); acc[2][2]=fmaf(a2,b2,acc[2][2]); acc[2][3]=fmaf(a2,b3,acc[2][3]);
      acc[3][0]=fmaf(a3,b0,acc[3][0]); acc[3][1]=fmaf(a3,b1,acc[3][1]); acc[3][2]=fmaf(a3,b2,acc[3][2]); acc[3][3]=fmaf(a3,b3,acc[3][3]);
    }
    __syncthreads();
  }
  #pragma unroll
  for (int i = 0; i < 4; ++i)
    #pragma unroll
    for (int j = 0; j < 4; ++j) {
      const int m = bm + ty*4 + i, n = bn + tx*4 + j;
      if (m < M && n < N) {
        float v = acc[i][j] + (bias ? bias[n] : 0.f);
        if (act == 1) v = fmaxf(v, 0.f);
        C[(size_t)m * ldc + n] = v;
      }
    }
}

__device__ inline float qdot4(const float4& a0, const float4& a1, const float4& a2, const float4& a3,
                              const float4& x0, const float4& x1, const float4& x2, const float4& x3) {
  float a = 0.f;
  a = fmaf(a0.x, x0.x, a); a = fmaf(a0.y, x0.y, a); a = fmaf(a0.z, x0.z, a); a = fmaf(a0.w, x0.w, a);
  a = fmaf(a1.x, x1.x, a); a = fmaf(a1.y, x1.y, a); a = fmaf(a1.z, x1.z, a); a = fmaf(a1.w, x1.w, a);
  a = fmaf(a2.x, x2.x, a); a = fmaf(a2.y, x2.y, a); a = fmaf(a2.z, x2.z, a); a = fmaf(a2.w, x2.w, a);
  a = fmaf(a3.x, x3.x, a); a = fmaf(a3.y, x3.y, a); a = fmaf(a3.z, x3.z, a); a = fmaf(a3.w, x3.w, a);
  return a;
}
__device__ inline float qdot2(const float4& a0, const float4& a1,
                              const float4& x0, const float4& x1) {
  float a = 0.f;
  a = fmaf(a0.x, x0.x, a); a = fmaf(a0.y, x0.y, a); a = fmaf(a0.z, x0.z, a); a = fmaf(a0.w, x0.w, a);
  a = fmaf(a1.x, x1.x, a); a = fmaf(a1.y, x1.y, a); a = fmaf(a1.z, x1.z, a); a = fmaf(a1.w, x1.w, a);
  return a;
}

// ---------------- persistent recurrence: 256 WGs x 512 thr, register-resident weights ----------------
// Identical compute structure to the proven r3 kernel; new hierarchical barrier +
// cross-stage register prefetch of S1's inputs (nh0/nh1/e0p/u0 carried from S3/S4).
__global__ __launch_bounds__(NT) void k_recur(
    float* __restrict__ ws,
    const float* __restrict__ Whh0, const float* __restrict__ bhh0,
    const float* __restrict__ Wih1, const float* __restrict__ bih1,
    const float* __restrict__ Whh1, const float* __restrict__ bhh1,
    const float* __restrict__ Wh,   const float* __restrict__ bh,
    const float* __restrict__ vh,   const float* __restrict__ vhb,
    const float* __restrict__ va,   const float* __restrict__ vab,
    const float* __restrict__ Wac)
{
  const float* Genc  = ws + WS_GENC;
  const float* gitok = ws + WS_GITOK;
  const float* Ex    = ws + WS_EX;
  float* H1    = ws + WS_H1;
  float* nh0g  = ws + WS_NH0;
  float* nh1g  = ws + WS_NH1;
  float* wbufg = ws + WS_WB;
  float* u0g   = ws + WS_U0;
  float* u1g   = ws + WS_U1;
  float* e0pg  = ws + WS_E0P;
  float* e1pg  = ws + WS_E1P;
  unsigned* bar = (unsigned*)(ws + WS_BARX);

  const int wg = blockIdx.x, tid = threadIdx.x;
  const int lane = tid & 63, wv = tid >> 6;

  __shared__ float xv[HID];      // staged state vector (h0n / nh0 / nh1)
  __shared__ float wl[S_LEN];    // staged attention weights
  __shared__ float cb[AD];       // c = Wa_c @ h0n
  __shared__ float sgit[12], sgh0[12], gh1l[12], sb0[12], sbh1[12], sacc[12];
  __shared__ float sred[8], sal[2], ssc[1];

  // ---- persistent register-resident weights ----
  float4 wreg[28];
  if (wv < 6) {
    #pragma unroll
    for (int r = 0; r < 2; ++r) {
      const int lr = 2 * wv + r;
      const int g = (lr >> 2) * HID + wg * 4 + (lr & 3);
      const float4* p0 = (const float4*)(Whh0 + (size_t)g * HID);
      const float4* p1 = (const float4*)(Wih1 + (size_t)g * HID);
      const float4* p2 = (const float4*)(Whh1 + (size_t)g * HID);
      const float4* pg = (const float4*)(Genc + (size_t)g * S_LEN);
      #pragma unroll
      for (int p = 0; p < 4; ++p) {
        wreg[r*4+p]      = p0[p*64 + lane];
        wreg[8 + r*4+p]  = p1[p*64 + lane];
        wreg[16 + r*4+p] = p2[p*64 + lane];
      }
      #pragma unroll
      for (int p = 0; p < 2; ++p) wreg[24 + r*2+p] = pg[p*64 + lane];
    }
  } else {
    const float* Wrow = (wv == 6) ? (Wh + (size_t)wg * HID) : (Wac + (size_t)wg * HID);
    const float4* p0 = (const float4*)Wrow;
    #pragma unroll
    for (int p = 0; p < 4; ++p) wreg[p] = p0[p*64 + lane];
    const int s = 2 * wg + (wv - 6);
    wreg[4] = ((const float4*)(Ex + (size_t)s * AD))[lane];
    wreg[5] = ((const float4*)va)[lane];
  }

  float i1r = 0.f, i1z = 0.f, i1n = 0.f;
  if (tid < 4) {
    const int j = wg * 4 + tid;
    i1r = bih1[j]; i1z = bih1[HID + j]; i1n = bih1[2 * HID + j];
  }
  if (tid < 12) {
    const int g = (tid >> 2) * HID + wg * 4 + (tid & 3);
    sb0[tid] = bhh0[g];
    const float bb = bhh1[g];
    sbh1[tid] = bb;
    gh1l[tid] = bb;          // gh1(t=0) = Whh1@0 + bhh1
    sgit[tid] = gitok[(size_t)0 * G3 + g];   // prefetch gitok for t=0
  }
  const float vhW = vh[wg], bhW = bh[wg];
  const float vabv = vab[0], vhb0 = vhb[0];
  unsigned b = 0;

  // cross-stage prefetch registers (S1(t) inputs carried from S3/S4(t-1); t=0 state is zero)
  float pa0 = 0.f, pa1 = 0.f;   // nh0(t-1)
  float pb0 = 0.f, pb1 = 0.f;   // nh1(t-1)
  float pep0 = 0.f, puu0 = 0.f; // e0p(t-1), u0(t-1)   (tid<256)
  float oldn = 0.f;             // own nh1[j] (tid<4)
  __syncthreads();

  const float4* XV4 = (const float4*)xv;
  const float4* WL4 = (const float4*)wl;
  const float4* CB4 = (const float4*)cb;

  #pragma unroll 1
  for (int t = 0; t < T_LEN; ++t) {
    // ========== S1: alpha; h0n; c; gh0 (LDS); publish w ==========
    {
      // only e1p/u1 (S4 products) are loaded here; the rest was prefetched
      float ep, uu1 = 0.f;
      if (tid < 256) { ep = pep0; uu1 = ldw(u1g + tid); }
      else           { ep = ldw(e1pg + (tid - 256)); }
      ep = wred64(ep);
      if (lane == 0) sred[wv] = ep;
      __syncthreads();
      if (tid == 0) {
        const float e0 = sred[0] + sred[1] + sred[2] + sred[3] + vhb0;
        const float e1 = sred[4] + sred[5] + sred[6] + sred[7] + vhb0;
        const float ea = __expf(e0), eb = __expf(e1);
        const float s = ea + eb;
        sal[0] = ea / s; sal[1] = eb / s;
      }
      __syncthreads();
      const float al0 = sal[0], al1 = sal[1];
      xv[tid]       = al0 * pa0 + al1 * pb0;
      xv[tid + 512] = al0 * pa1 + al1 * pb1;
      if (tid < AD) cb[tid] = al0 * puu0 + al1 * uu1;
      __syncthreads();
      if (wv < 6) {
        const float4 x0 = XV4[lane], x1 = XV4[64+lane], x2 = XV4[128+lane], x3 = XV4[192+lane];
        float accA = qdot4(wreg[0], wreg[1], wreg[2], wreg[3], x0, x1, x2, x3);
        float accB = qdot4(wreg[4], wreg[5], wreg[6], wreg[7], x0, x1, x2, x3);
        accA = wred64(accA); accB = wred64(accB);
        if (lane == 0) {
          sgh0[2*wv]     = accA + sb0[2*wv];
          sgh0[2*wv + 1] = accB + sb0[2*wv + 1];
        }
      } else {
        const float4 e4 = wreg[4], v4 = wreg[5], c4 = CB4[lane];
        float acc = v4.x * fast_tanh(e4.x + c4.x) + v4.y * fast_tanh(e4.y + c4.y)
                  + v4.z * fast_tanh(e4.z + c4.z) + v4.w * fast_tanh(e4.w + c4.w);
        acc = wred64(acc);
        if (lane == 0) stw(wbufg + 2*wg + (wv - 6), __expf(acc + vabv));
      }
    }
    gbar(bar, wg, ++b);

    // ========== S2: nh0 = GRU0((Genc @ w)/sum + gi_tok[t], gh0, h0n) ==========
    {
      const float wval = ldw(wbufg + tid);
      wl[tid] = wval;
      const float ps = wred64(wval);
      if (lane == 0) sred[wv] = ps;
      __syncthreads();
      if (tid == 0) {
        float s = 0.f;
        #pragma unroll
        for (int i = 0; i < 8; ++i) s += sred[i];
        ssc[0] = 1.f / s;
      }
      if (wv < 6) {
        const float4 w0 = WL4[lane], w1 = WL4[64 + lane];
        float accA = qdot2(wreg[24], wreg[25], w0, w1);
        float accB = qdot2(wreg[26], wreg[27], w0, w1);
        accA = wred64(accA); accB = wred64(accB);
        if (lane == 0) { sacc[2*wv] = accA; sacc[2*wv + 1] = accB; }
      }
      __syncthreads();
      if (tid < 4) {
        const float inv = ssc[0];
        const float d0 = sacc[tid]     * inv + sgit[tid];
        const float d1 = sacc[4 + tid] * inv + sgit[4 + tid];
        const float d2 = sacc[8 + tid] * inv + sgit[8 + tid];
        const float rg = fast_sigmoid(d0 + sgh0[tid]);
        const float zg = fast_sigmoid(d1 + sgh0[4 + tid]);
        const float ng = fast_tanh(d2 + rg * sgh0[8 + tid]);
        const float h0j = xv[wg * 4 + tid];
        stw(nh0g + wg * 4 + tid, (1.f - zg) * ng + zg * h0j);
      }
    }
    gbar(bar, wg, ++b);

    // ========== S3: nh1 = GRU1(Wih1@nh0, gh1_prev, nh1_prev); e0, u0 ==========
    {
      const float x0 = ldw(nh0g + tid), x1 = ldw(nh0g + 512 + tid);
      pa0 = x0; pa1 = x1;                   // prefetch: nh0(t) for S1(t+1)
      xv[tid] = x0; xv[tid + 512] = x1;
      __syncthreads();
      const float4 y0 = XV4[lane], y1 = XV4[64+lane], y2 = XV4[128+lane], y3 = XV4[192+lane];
      if (wv < 6) {
        float accA = qdot4(wreg[8],  wreg[9],  wreg[10], wreg[11], y0, y1, y2, y3);
        float accB = qdot4(wreg[12], wreg[13], wreg[14], wreg[15], y0, y1, y2, y3);
        accA = wred64(accA); accB = wred64(accB);
        if (lane == 0) { sacc[2*wv] = accA; sacc[2*wv + 1] = accB; }
      } else {
        float acc = qdot4(wreg[0], wreg[1], wreg[2], wreg[3], y0, y1, y2, y3);
        acc = wred64(acc);
        if (lane == 0) {
          if (wv == 6) stw(e0pg + wg, vhW * fast_tanh(acc + bhW));
          else         stw(u0g + wg, acc);
        }
      }
      __syncthreads();
      if (tid < 4) {
        const float gr = sacc[tid]     + i1r;
        const float gz = sacc[4 + tid] + i1z;
        const float gn = sacc[8 + tid] + i1n;
        const float rg = fast_sigmoid(gr + gh1l[tid]);
        const float zg = fast_sigmoid(gz + gh1l[4 + tid]);
        const float ng = fast_tanh(gn + rg * gh1l[8 + tid]);
        const float nv = (1.f - zg) * ng + zg * oldn;
        oldn = nv;                          // carry own nh1[j] locally
        stw(nh1g + wg * 4 + tid, nv);
        H1[(size_t)t * HID + wg * 4 + tid] = nv;
      }
    }
    gbar(bar, wg, ++b);

    // ========== S4: gh1_next; e1, u1; prefetch S1(t+1) inputs ==========
    {
      const float x0 = ldw(nh1g + tid), x1 = ldw(nh1g + 512 + tid);
      pb0 = x0; pb1 = x1;                   // prefetch: nh1(t) for S1(t+1)
      xv[tid] = x0; xv[tid + 512] = x1;
      __syncthreads();
      // prefetch e0p/u0 (S3 products, barrier3-ordered) + gitok(t+1) under compute
      if (tid < 256) { pep0 = ldw(e0pg + tid); puu0 = ldw(u0g + tid); }
      if (tid < 12) {
        const int tn = (t + 1 < T_LEN) ? t + 1 : t;
        sgit[tid] = gitok[(size_t)tn * G3 + (tid >> 2) * HID + wg * 4 + (tid & 3)];
      }
      const float4 y0 = XV4[lane], y1 = XV4[64+lane], y2 = XV4[128+lane], y3 = XV4[192+lane];
      if (wv < 6) {
        float accA = qdot4(wreg[16], wreg[17], wreg[18], wreg[19], y0, y1, y2, y3);
        float accB = qdot4(wreg[20], wreg[21], wreg[22], wreg[23], y0, y1, y2, y3);
        accA = wred64(accA); accB = wred64(accB);
        if (lane == 0) {
          gh1l[2*wv]     = accA + sbh1[2*wv];
          gh1l[2*wv + 1] = accB + sbh1[2*wv + 1];
        }
      } else {
        float acc = qdot4(wreg[0], wreg[1], wreg[2], wreg[3], y0, y1, y2, y3);
        acc = wred64(acc);
        if (lane == 0) {
          if (wv == 6) stw(e1pg + wg, vhW * fast_tanh(acc + bhW));
          else         stw(u1g + wg, acc);
        }
      }
    }
    gbar(bar, wg, ++b);
  }
}

// ---------------- output head: logits -> exp -> per-wave row partials ----------------
__global__ __launch_bounds__(256) void k_head(
    const float* __restrict__ FC1, const float* __restrict__ Wf2,
    const float* __restrict__ bf2, float* __restrict__ out, float* __restrict__ rowp)
{
  __shared__ float fcb[256 * 32];
  const int v = blockIdx.x * 256 + threadIdx.x;
  const bool ok = v < VOC;
  float wf[32];
  float bb = 0.f;
  if (ok) {
    const float4* W4 = (const float4*)(Wf2 + (size_t)v * 32);
    #pragma unroll
    for (int q = 0; q < 8; ++q) ((float4*)wf)[q] = W4[q];
    bb = bf2[v];
  }
  const int wv = threadIdx.x >> 6;
  #pragma unroll 1
  for (int half = 0; half < 2; ++half) {
    __syncthreads();
    for (int i = threadIdx.x; i < 256 * 32 / 4; i += 256)
      ((float4*)fcb)[i] = ((const float4*)(FC1 + half * 256 * 32))[i];
    __syncthreads();
    #pragma unroll 1
    for (int tt = 0; tt < 256; ++tt) {
      const int t = half * 256 + tt;
      const float4* f4 = (const float4*)(fcb + tt * 32);
      float acc = bb;
      #pragma unroll
      for (int q = 0; q < 8; ++q) {
        float4 f = f4[q];
        acc = fmaf(wf[4*q+0], f.x, acc);
        acc = fmaf(wf[4*q+1], f.y, acc);
        acc = fmaf(wf[4*q+2], f.z, acc);
        acc = fmaf(wf[4*q+3], f.w, acc);
      }
      const float w = ok ? __expf(acc) : 0.f;
      if (ok) out[(size_t)t * VOC + v] = w;
      float r = wred64(w);
      if ((threadIdx.x & 63) == 0)
        rowp[(size_t)t * NPART + (size_t)blockIdx.x * 4 + wv] = r;
    }
  }
}

__global__ __launch_bounds__(256) void k_rowsum(const float* __restrict__ rowp, float* __restrict__ inv) {
  const int t = blockIdx.x;
  float acc = 0.f;
  for (int i = threadIdx.x; i < NPART; i += 256) acc += rowp[(size_t)t * NPART + i];
  acc = wred64(acc);
  __shared__ float sr[4];
  if ((threadIdx.x & 63) == 0) sr[threadIdx.x >> 6] = acc;
  __syncthreads();
  if (threadIdx.x == 0) inv[t] = 1.f / (sr[0] + sr[1] + sr[2] + sr[3]);
}

__global__ __launch_bounds__(256) void k_scale(float* __restrict__ out, const float* __restrict__ inv) {
  const int t = blockIdx.y;
  const float s = inv[t];
  const size_t base = (size_t)t * VOC;
  const int v0 = blockIdx.x * 2048 + threadIdx.x;
  #pragma unroll
  for (int k = 0; k < 8; ++k) {
    const int v = v0 + k * 256;
    if (v < VOC) out[base + v] *= s;
  }
}

extern "C" void kernel_launch(void* const* d_in, const int* in_sizes, int n_in,
                              void* d_out, int out_size, void* d_ws, size_t ws_size,
                              hipStream_t stream) {
  const int*   dec  = (const int*)  d_in[0];
  const float* enc  = (const float*)d_in[1];
  const float* emb  = (const float*)d_in[2];
  const float* Wax  = (const float*)d_in[3];
  const float* Wac  = (const float*)d_in[4];
  const float* ba   = (const float*)d_in[5];
  const float* va   = (const float*)d_in[6];
  const float* vab  = (const float*)d_in[7];
  const float* Wih0 = (const float*)d_in[8];
  const float* bih0 = (const float*)d_in[9];
  const float* Whh0 = (const float*)d_in[10];
  const float* bhh0 = (const float*)d_in[11];
  const float* Wih1 = (const float*)d_in[12];
  const float* bih1 = (const float*)d_in[13];
  const float* Whh1 = (const float*)d_in[14];
  const float* bhh1 = (const float*)d_in[15];
  const float* Wh   = (const float*)d_in[16];
  const float* bh   = (const float*)d_in[17];
  const float* vh   = (const float*)d_in[18];
  const float* vhb  = (const float*)d_in[19];
  const float* Wf1  = (const float*)d_in[20];
  const float* bf1  = (const float*)d_in[21];
  const float* Wf2  = (const float*)d_in[22];
  const float* bf2  = (const float*)d_in[23];
  float* out = (float*)d_out;
  float* ws  = (float*)d_ws;

  k_init<<<1, 256, 0, stream>>>(ws);

  // Genc[r][s] = Wih0[r, :1024] . enc[s]          (M=3072, N=512)
  k_gemm<<<dim3(8, 48), 256, 0, stream>>>(Wih0, 2048, nullptr, enc, 1024, 0,
                                          nullptr, ws + WS_GENC, 512, G3, S_LEN, 0);
  // gi_tok[t][r] = emb[dec[t]] . Wih0[r, 1024:] + bih0[r]   (M=512, N=3072)
  k_gemm<<<dim3(48, 8), 256, 0, stream>>>(emb, 1024, dec, Wih0, 2048, 1024,
                                          bih0, ws + WS_GITOK, G3, T_LEN, G3, 0);
  // Ex[s][i] = enc[s] . Wa_x[i] + ba[i]           (M=512, N=256)
  k_gemm<<<dim3(4, 8), 256, 0, stream>>>(enc, 1024, nullptr, Wax, 1024, 0,
                                         ba, ws + WS_EX, AD, S_LEN, AD, 0);

  k_recur<<<NWG, NT, 0, stream>>>(ws, Whh0, bhh0, Wih1, bih1, Whh1, bhh1,
                                  Wh, bh, vh, vhb, va, vab, Wac);

  // FC1[t] = relu(Wf1 @ H1[t] + bf1)              (M=512, N=32)
  k_gemm<<<dim3(1, 8), 256, 0, stream>>>(ws + WS_H1, 1024, nullptr, Wf1, 1024, 0,
                                         bf1, ws + WS_FC1, 32, T_LEN, 32, 1);

  k_head<<<197, 256, 0, stream>>>(ws + WS_FC1, Wf2, bf2, out, ws + WS_ROWP);
  k_rowsum<<<512, 256, 0, stream>>>(ws + WS_ROWP, ws + WS_INV);
  k_scale<<<dim3(25, 512), 256, 0, stream>>>(out, ws + WS_INV);
}

// Round 11
// 5512.696 us; speedup vs baseline: 2.6724x; 2.1630x over previous
//
#include <hip/hip_runtime.h>
#include <cstdint>
#include <cstddef>

#define T_LEN 512
#define S_LEN 512
#define HID   1024
#define AD    256
#define VOC   50257
#define G3    3072
#define NWG   256
#define NT    512
#define NPART (197*4)

// ---------------- workspace layout (float offsets) ----------------
#define WS_GENC   0
#define WS_GITOK  (WS_GENC + G3*S_LEN)          // [512][3072]
#define WS_EX     (WS_GITOK + T_LEN*G3)         // [512][256]
#define WS_H1     (WS_EX + S_LEN*AD)            // [512][1024]
#define WS_FC1    (WS_H1 + T_LEN*HID)           // [512][32]
#define WS_NH0    (WS_FC1 + T_LEN*32)
#define WS_NH1    (WS_NH0 + HID)
#define WS_WB     (WS_NH1 + HID)                 // 512
#define WS_U0     (WS_WB + S_LEN)                // 256
#define WS_U1     (WS_U0 + AD)                   // 256
#define WS_E0P    (WS_U1 + AD)                   // 256
#define WS_E1P    (WS_E0P + 256)                 // 256
#define WS_BARX   (WS_E1P + 256)                 // 384 uints (256 slots + gen)
#define WS_ROWP   (WS_BARX + 384)                // [512][788]
#define WS_INV    (WS_ROWP + T_LEN*NPART)
#define WS_END    (WS_INV + T_LEN)

__device__ inline float wred64(float v) {
  v += __shfl_xor(v, 32, 64); v += __shfl_xor(v, 16, 64); v += __shfl_xor(v, 8, 64);
  v += __shfl_xor(v, 4, 64);  v += __shfl_xor(v, 2, 64);  v += __shfl_xor(v, 1, 64);
  return v;
}

__device__ inline float fast_sigmoid(float x) { return 1.f / (1.f + __expf(-x)); }
__device__ inline float fast_tanh(float x) {
  float e = __expf(2.f * x);
  return 1.f - 2.f / (e + 1.f);
}

// agent-scope (LLC-coherent) state accessors
__device__ inline float ldw(const float* p) {
  return __uint_as_float(__hip_atomic_load((const unsigned int*)p,
                                           __ATOMIC_RELAXED, __HIP_MEMORY_SCOPE_AGENT));
}
__device__ inline void stw(float* p, float v) {
  __hip_atomic_store((unsigned int*)p, __float_as_uint(v),
                     __ATOMIC_RELAXED, __HIP_MEMORY_SCOPE_AGENT);
}
__device__ inline unsigned ldu(const unsigned* p) {
  return __hip_atomic_load(p, __ATOMIC_RELAXED, __HIP_MEMORY_SCOPE_AGENT);
}
__device__ inline void stu(unsigned* p, unsigned v) {
  __hip_atomic_store(p, v, __ATOMIC_RELAXED, __HIP_MEMORY_SCOPE_AGENT);
}

// r3's proven checker barrier, split into arrive/wait so deferrable compute
// (gh0/gh1 matvecs, consumed only after the NEXT barrier) overlaps the sync.
// arrive: __syncthreads drains this WG's agent-scope stores, then slot store.
// wait:   WG0's 256 threads poll all slots, publish gen; others poll gen.
__device__ inline void gbar_arrive(unsigned* slot, unsigned b) {
  __syncthreads();
  if (threadIdx.x == 0) stu(slot + blockIdx.x, b);
}
__device__ inline void gbar_wait(unsigned* slot, unsigned* gen, unsigned b) {
  if (blockIdx.x == 0) {
    if (threadIdx.x < NWG) {
      while (ldu(slot + threadIdx.x) < b) __builtin_amdgcn_s_sleep(1);
    }
    __syncthreads();
    if (threadIdx.x == 0) stu(gen, b);
  } else {
    if (threadIdx.x == 0) {
      while (ldu(gen) < b) __builtin_amdgcn_s_sleep(1);
    }
  }
  __syncthreads();
}

// ---------------- init: zero recurrent state + barrier ----------------
__global__ void k_init(float* ws) {
  const int tid = threadIdx.x;
  for (int i = tid; i < HID; i += 256) { ws[WS_NH0 + i] = 0.f; ws[WS_NH1 + i] = 0.f; }
  if (tid < AD) { ws[WS_U0 + tid] = 0.f; ws[WS_U1 + tid] = 0.f; }
  ws[WS_E0P + tid] = 0.f;   // 256
  ws[WS_E1P + tid] = 0.f;   // 256
  for (int i = tid; i < 384; i += 256) ((unsigned*)(ws + WS_BARX))[i] = 0u;
}

// ---------------- generic tiled fp32 GEMM (pre/post passes) ----------------
__global__ __launch_bounds__(256) void k_gemm(
    const float* __restrict__ A, int lda, const int* __restrict__ gidx,
    const float* __restrict__ B, int ldb, int kofs,
    const float* __restrict__ bias, float* __restrict__ C, int ldc,
    int M, int N, int act)
{
  __shared__ float As[64][33];
  __shared__ float Bs[64][33];
  const int bm = blockIdx.y * 64, bn = blockIdx.x * 64;
  const int tx = threadIdx.x & 15, ty = threadIdx.x >> 4;
  float acc[4][4] = {};
  const int lin = threadIdx.x * 8;
  const int lr = lin >> 5;
  const int lc = lin & 31;
  for (int k0 = 0; k0 < 1024; k0 += 32) {
    {
      const int gm = bm + lr;
      float4 v0 = {0,0,0,0}, v1 = {0,0,0,0};
      if (gm < M) {
        const int row = gidx ? gidx[gm] : gm;
        const float* p = A + (size_t)row * lda + k0 + lc;
        v0 = *(const float4*)p; v1 = *(const float4*)(p + 4);
      }
      As[lr][lc+0]=v0.x; As[lr][lc+1]=v0.y; As[lr][lc+2]=v0.z; As[lr][lc+3]=v0.w;
      As[lr][lc+4]=v1.x; As[lr][lc+5]=v1.y; As[lr][lc+6]=v1.z; As[lr][lc+7]=v1.w;
    }
    {
      const int gn = bn + lr;
      float4 v0 = {0,0,0,0}, v1 = {0,0,0,0};
      if (gn < N) {
        const float* p = B + (size_t)gn * ldb + kofs + k0 + lc;
        v0 = *(const float4*)p; v1 = *(const float4*)(p + 4);
      }
      Bs[lr][lc+0]=v0.x; Bs[lr][lc+1]=v0.y; Bs[lr][lc+2]=v0.z; Bs[lr][lc+3]=v0.w;
      Bs[lr][lc+4]=v1.x; Bs[lr][lc+5]=v1.y; Bs[lr][lc+6]=v1.z; Bs[lr][lc+7]=v1.w;
    }
    __syncthreads();
    #pragma unroll
    for (int kk = 0; kk < 32; ++kk) {
      float a0 = As[ty*4+0][kk], a1 = As[ty*4+1][kk], a2 = As[ty*4+2][kk], a3 = As[ty*4+3][kk];
      float b0 = Bs[tx*4+0][kk], b1 = Bs[tx*4+1][kk], b2 = Bs[tx*4+2][kk], b3 = Bs[tx*4+3][kk];
      acc[0][0]=fmaf(a0,b0,acc[0][0]); acc[0][1]=fmaf(a0,b1,acc[0][1]); acc[0][2]=fmaf(a0,b2,acc[0][2]); acc[0][3]=fmaf(a0,b3,acc[0][3]);
      acc[1][0]=fmaf(a1,b0,acc[1][0]); acc[1][1]=fmaf(a1,b1,acc[1][1]); acc[1][2]=fmaf(a1,b2,acc[1][2]); acc[1][3]=fmaf(a1,b3,acc[1][3]);
      acc[2][0]=fmaf(a2,b0,acc[2][0]); acc[2][1]=fmaf(a2,b1,acc[2][1]); acc[2][2]=fmaf(a2,b2,acc[2][2]); acc[2][3]=fmaf(a2,b3,acc[2][3]);
      acc[3][0]=fmaf(a3,b0,acc[3][0]); acc[3][1]=fmaf(a3,b1,acc[3][1]); acc[3][2]=fmaf(a3,b2,acc[3][2]); acc[3][3]=fmaf(a3,b3,acc[3][3]);
    }
    __syncthreads();
  }
  #pragma unroll
  for (int i = 0; i < 4; ++i)
    #pragma unroll
    for (int j = 0; j < 4; ++j) {
      const int m = bm + ty*4 + i, n = bn + tx*4 + j;
      if (m < M && n < N) {
        float v = acc[i][j] + (bias ? bias[n] : 0.f);
        if (act == 1) v = fmaxf(v, 0.f);
        C[(size_t)m * ldc + n] = v;
      }
    }
}

__device__ inline float qdot4(const float4& a0, const float4& a1, const float4& a2, const float4& a3,
                              const float4& x0, const float4& x1, const float4& x2, const float4& x3) {
  float a = 0.f;
  a = fmaf(a0.x, x0.x, a); a = fmaf(a0.y, x0.y, a); a = fmaf(a0.z, x0.z, a); a = fmaf(a0.w, x0.w, a);
  a = fmaf(a1.x, x1.x, a); a = fmaf(a1.y, x1.y, a); a = fmaf(a1.z, x1.z, a); a = fmaf(a1.w, x1.w, a);
  a = fmaf(a2.x, x2.x, a); a = fmaf(a2.y, x2.y, a); a = fmaf(a2.z, x2.z, a); a = fmaf(a2.w, x2.w, a);
  a = fmaf(a3.x, x3.x, a); a = fmaf(a3.y, x3.y, a); a = fmaf(a3.z, x3.z, a); a = fmaf(a3.w, x3.w, a);
  return a;
}
__device__ inline float qdot2(const float4& a0, const float4& a1,
                              const float4& x0, const float4& x1) {
  float a = 0.f;
  a = fmaf(a0.x, x0.x, a); a = fmaf(a0.y, x0.y, a); a = fmaf(a0.z, x0.z, a); a = fmaf(a0.w, x0.w, a);
  a = fmaf(a1.x, x1.x, a); a = fmaf(a1.y, x1.y, a); a = fmaf(a1.z, x1.z, a); a = fmaf(a1.w, x1.w, a);
  return a;
}

// ---------------- persistent recurrence: 256 WGs x 512 thr, register-resident weights ----------------
// Byte-identical compute to the proven round-3 kernel; only change: split-phase
// barrier with gh0 (S1) and gh1 (S4) matvecs deferred into the barrier-wait window.
__global__ __launch_bounds__(NT) void k_recur(
    float* __restrict__ ws,
    const float* __restrict__ Whh0, const float* __restrict__ bhh0,
    const float* __restrict__ Wih1, const float* __restrict__ bih1,
    const float* __restrict__ Whh1, const float* __restrict__ bhh1,
    const float* __restrict__ Wh,   const float* __restrict__ bh,
    const float* __restrict__ vh,   const float* __restrict__ vhb,
    const float* __restrict__ va,   const float* __restrict__ vab,
    const float* __restrict__ Wac)
{
  const float* Genc  = ws + WS_GENC;
  const float* gitok = ws + WS_GITOK;
  const float* Ex    = ws + WS_EX;
  float* H1    = ws + WS_H1;
  float* nh0g  = ws + WS_NH0;
  float* nh1g  = ws + WS_NH1;
  float* wbufg = ws + WS_WB;
  float* u0g   = ws + WS_U0;
  float* u1g   = ws + WS_U1;
  float* e0pg  = ws + WS_E0P;
  float* e1pg  = ws + WS_E1P;
  unsigned* slot = (unsigned*)(ws + WS_BARX);
  unsigned* gen  = slot + NWG;

  const int wg = blockIdx.x, tid = threadIdx.x;
  const int lane = tid & 63, wv = tid >> 6;

  __shared__ float xv[HID];      // staged state vector (h0n / nh0 / nh1)
  __shared__ float wl[S_LEN];    // staged attention weights
  __shared__ float cb[AD];       // c = Wa_c @ h0n
  __shared__ float sgit[12], sgh0[12], gh1l[12], sb0[12], sbh1[12], sacc[12];
  __shared__ float sred[8], sal[2], ssc[1];

  // ---- persistent register-resident weights ----
  float4 wreg[28];
  if (wv < 6) {
    #pragma unroll
    for (int r = 0; r < 2; ++r) {
      const int lr = 2 * wv + r;
      const int g = (lr >> 2) * HID + wg * 4 + (lr & 3);
      const float4* p0 = (const float4*)(Whh0 + (size_t)g * HID);
      const float4* p1 = (const float4*)(Wih1 + (size_t)g * HID);
      const float4* p2 = (const float4*)(Whh1 + (size_t)g * HID);
      const float4* pg = (const float4*)(Genc + (size_t)g * S_LEN);
      #pragma unroll
      for (int p = 0; p < 4; ++p) {
        wreg[r*4+p]      = p0[p*64 + lane];
        wreg[8 + r*4+p]  = p1[p*64 + lane];
        wreg[16 + r*4+p] = p2[p*64 + lane];
      }
      #pragma unroll
      for (int p = 0; p < 2; ++p) wreg[24 + r*2+p] = pg[p*64 + lane];
    }
  } else {
    const float* Wrow = (wv == 6) ? (Wh + (size_t)wg * HID) : (Wac + (size_t)wg * HID);
    const float4* p0 = (const float4*)Wrow;
    #pragma unroll
    for (int p = 0; p < 4; ++p) wreg[p] = p0[p*64 + lane];
    const int s = 2 * wg + (wv - 6);
    wreg[4] = ((const float4*)(Ex + (size_t)s * AD))[lane];
    wreg[5] = ((const float4*)va)[lane];
  }

  // combiner biases (threads 0..3, jl = tid)
  float i1r = 0.f, i1z = 0.f, i1n = 0.f;
  if (tid < 4) {
    const int j = wg * 4 + tid;
    i1r = bih1[j]; i1z = bih1[HID + j]; i1n = bih1[2 * HID + j];
  }
  if (tid < 12) {
    const int g = (tid >> 2) * HID + wg * 4 + (tid & 3);
    sb0[tid] = bhh0[g];
    const float bb = bhh1[g];
    sbh1[tid] = bb;
    gh1l[tid] = bb;          // gh1(t=0) = Whh1@0 + bhh1
  }
  const float vhW = vh[wg], bhW = bh[wg];
  const float vabv = vab[0], vhb0 = vhb[0];
  unsigned b = 0;
  __syncthreads();

  const float4* XV4 = (const float4*)xv;
  const float4* WL4 = (const float4*)wl;
  const float4* CB4 = (const float4*)cb;

  #pragma unroll 1
  for (int t = 0; t < T_LEN; ++t) {
    // ========== S1: alpha; h0n; c; publish w; [deferred: gh0] ==========
    {
      // issue all cross-WG state loads up front
      const float a0 = ldw(nh0g + tid), a1 = ldw(nh0g + 512 + tid);
      const float b0 = ldw(nh1g + tid), b1 = ldw(nh1g + 512 + tid);
      float uu0 = 0.f, uu1 = 0.f;
      if (tid < AD) { uu0 = ldw(u0g + tid); uu1 = ldw(u1g + tid); }
      float ep = (tid < 256) ? ldw(e0pg + tid) : ldw(e1pg + tid - 256);
      if (tid < 12)
        sgit[tid] = gitok[(size_t)t * G3 + (tid >> 2) * HID + wg * 4 + (tid & 3)];
      ep = wred64(ep);
      if (lane == 0) sred[wv] = ep;
      __syncthreads();
      if (tid == 0) {
        const float e0 = sred[0] + sred[1] + sred[2] + sred[3] + vhb0;
        const float e1 = sred[4] + sred[5] + sred[6] + sred[7] + vhb0;
        const float ea = __expf(e0), eb = __expf(e1);
        const float s = ea + eb;
        sal[0] = ea / s; sal[1] = eb / s;
      }
      __syncthreads();
      const float al0 = sal[0], al1 = sal[1];
      xv[tid]       = al0 * a0 + al1 * b0;
      xv[tid + 512] = al0 * a1 + al1 * b1;
      if (tid < AD) cb[tid] = al0 * uu0 + al1 * uu1;
      __syncthreads();
      if (wv >= 6) {
        const float4 e4 = wreg[4], v4 = wreg[5], c4 = CB4[lane];
        const float s0 = fast_tanh(e4.x + c4.x);
        const float s1 = fast_tanh(e4.y + c4.y);
        const float s2 = fast_tanh(e4.z + c4.z);
        const float s3 = fast_tanh(e4.w + c4.w);
        float acc = v4.x*s0 + v4.y*s1 + v4.z*s2 + v4.w*s3;
        acc = wred64(acc);
        if (lane == 0) stw(wbufg + 2*wg + (wv - 6), __expf(acc + vabv));
      }
    }
    ++b;
    gbar_arrive(slot, b);
    if (wv < 6) {   // deferred gh0: xv stable until after wait; sgh0 read at S2 post-wait
      const float4 x0 = XV4[lane], x1 = XV4[64+lane], x2 = XV4[128+lane], x3 = XV4[192+lane];
      float accA = qdot4(wreg[0], wreg[1], wreg[2], wreg[3], x0, x1, x2, x3);
      float accB = qdot4(wreg[4], wreg[5], wreg[6], wreg[7], x0, x1, x2, x3);
      accA = wred64(accA); accB = wred64(accB);
      if (lane == 0) {
        sgh0[2*wv]     = accA + sb0[2*wv];
        sgh0[2*wv + 1] = accB + sb0[2*wv + 1];
      }
    }
    gbar_wait(slot, gen, b);

    // ========== S2: nh0 = GRU0((Genc @ w)/sum + gi_tok[t], gh0, h0n) ==========
    {
      const float wval = ldw(wbufg + tid);
      wl[tid] = wval;
      const float ps = wred64(wval);
      if (lane == 0) sred[wv] = ps;
      __syncthreads();
      if (tid == 0) {
        float s = 0.f;
        #pragma unroll
        for (int i = 0; i < 8; ++i) s += sred[i];
        ssc[0] = 1.f / s;
      }
      if (wv < 6) {
        const float4 w0 = WL4[lane], w1 = WL4[64 + lane];
        float accA = qdot2(wreg[24], wreg[25], w0, w1);
        float accB = qdot2(wreg[26], wreg[27], w0, w1);
        accA = wred64(accA); accB = wred64(accB);
        if (lane == 0) { sacc[2*wv] = accA; sacc[2*wv + 1] = accB; }
      }
      __syncthreads();
      if (tid < 4) {
        const float inv = ssc[0];
        const float d0 = sacc[tid]     * inv + sgit[tid];
        const float d1 = sacc[4 + tid] * inv + sgit[4 + tid];
        const float d2 = sacc[8 + tid] * inv + sgit[8 + tid];
        const float rg = fast_sigmoid(d0 + sgh0[tid]);
        const float zg = fast_sigmoid(d1 + sgh0[4 + tid]);
        const float ng = fast_tanh(d2 + rg * sgh0[8 + tid]);
        const float h0j = xv[wg * 4 + tid];
        stw(nh0g + wg * 4 + tid, (1.f - zg) * ng + zg * h0j);
      }
    }
    ++b;
    gbar_arrive(slot, b);
    gbar_wait(slot, gen, b);

    // ========== S3: nh1 = GRU1(Wih1@nh0, gh1_prev, nh1_prev); e0, u0 ==========
    {
      const float x0 = ldw(nh0g + tid), x1 = ldw(nh0g + 512 + tid);
      const float oldn = (tid < 4) ? ldw(nh1g + wg * 4 + tid) : 0.f;
      xv[tid] = x0; xv[tid + 512] = x1;
      __syncthreads();
      const float4 y0 = XV4[lane], y1 = XV4[64+lane], y2 = XV4[128+lane], y3 = XV4[192+lane];
      if (wv < 6) {
        float accA = qdot4(wreg[8],  wreg[9],  wreg[10], wreg[11], y0, y1, y2, y3);
        float accB = qdot4(wreg[12], wreg[13], wreg[14], wreg[15], y0, y1, y2, y3);
        accA = wred64(accA); accB = wred64(accB);
        if (lane == 0) { sacc[2*wv] = accA; sacc[2*wv + 1] = accB; }
      } else {
        float acc = qdot4(wreg[0], wreg[1], wreg[2], wreg[3], y0, y1, y2, y3);
        acc = wred64(acc);
        if (lane == 0) {
          if (wv == 6) stw(e0pg + wg, vhW * fast_tanh(acc + bhW));
          else         stw(u0g + wg, acc);
        }
      }
      __syncthreads();
      if (tid < 4) {
        const float gr = sacc[tid]     + i1r;
        const float gz = sacc[4 + tid] + i1z;
        const float gn = sacc[8 + tid] + i1n;
        const float rg = fast_sigmoid(gr + gh1l[tid]);
        const float zg = fast_sigmoid(gz + gh1l[4 + tid]);
        const float ng = fast_tanh(gn + rg * gh1l[8 + tid]);
        const float nv = (1.f - zg) * ng + zg * oldn;
        stw(nh1g + wg * 4 + tid, nv);
        H1[(size_t)t * HID + wg * 4 + tid] = nv;
      }
    }
    ++b;
    gbar_arrive(slot, b);
    gbar_wait(slot, gen, b);

    // ========== S4: publish e1, u1; [deferred: gh1_next = Whh1 @ nh1 + bhh1] ==========
    {
      const float x0 = ldw(nh1g + tid), x1 = ldw(nh1g + 512 + tid);
      xv[tid] = x0; xv[tid + 512] = x1;
      __syncthreads();
      if (wv >= 6) {
        const float4 y0 = XV4[lane], y1 = XV4[64+lane], y2 = XV4[128+lane], y3 = XV4[192+lane];
        float acc = qdot4(wreg[0], wreg[1], wreg[2], wreg[3], y0, y1, y2, y3);
        acc = wred64(acc);
        if (lane == 0) {
          if (wv == 6) stw(e1pg + wg, vhW * fast_tanh(acc + bhW));
          else         stw(u1g + wg, acc);
        }
      }
    }
    ++b;
    gbar_arrive(slot, b);
    if (wv < 6) {   // deferred gh1: xv stable until S1(t+1) writes (post-wait); gh1l read at S3(t+1)
      const float4 y0 = XV4[lane], y1 = XV4[64+lane], y2 = XV4[128+lane], y3 = XV4[192+lane];
      float accA = qdot4(wreg[16], wreg[17], wreg[18], wreg[19], y0, y1, y2, y3);
      float accB = qdot4(wreg[20], wreg[21], wreg[22], wreg[23], y0, y1, y2, y3);
      accA = wred64(accA); accB = wred64(accB);
      if (lane == 0) {
        gh1l[2*wv]     = accA + sbh1[2*wv];
        gh1l[2*wv + 1] = accB + sbh1[2*wv + 1];
      }
    }
    gbar_wait(slot, gen, b);
  }
}

// ---------------- output head: logits -> exp -> per-wave row partials ----------------
__global__ __launch_bounds__(256) void k_head(
    const float* __restrict__ FC1, const float* __restrict__ Wf2,
    const float* __restrict__ bf2, float* __restrict__ out, float* __restrict__ rowp)
{
  __shared__ float fcb[256 * 32];
  const int v = blockIdx.x * 256 + threadIdx.x;
  const bool ok = v < VOC;
  float wf[32];
  float bb = 0.f;
  if (ok) {
    const float4* W4 = (const float4*)(Wf2 + (size_t)v * 32);
    #pragma unroll
    for (int q = 0; q < 8; ++q) ((float4*)wf)[q] = W4[q];
    bb = bf2[v];
  }
  const int wv = threadIdx.x >> 6;
  #pragma unroll 1
  for (int half = 0; half < 2; ++half) {
    __syncthreads();
    for (int i = threadIdx.x; i < 256 * 32 / 4; i += 256)
      ((float4*)fcb)[i] = ((const float4*)(FC1 + half * 256 * 32))[i];
    __syncthreads();
    #pragma unroll 1
    for (int tt = 0; tt < 256; ++tt) {
      const int t = half * 256 + tt;
      const float4* f4 = (const float4*)(fcb + tt * 32);
      float acc = bb;
      #pragma unroll
      for (int q = 0; q < 8; ++q) {
        float4 f = f4[q];
        acc = fmaf(wf[4*q+0], f.x, acc);
        acc = fmaf(wf[4*q+1], f.y, acc);
        acc = fmaf(wf[4*q+2], f.z, acc);
        acc = fmaf(wf[4*q+3], f.w, acc);
      }
      const float w = ok ? __expf(acc) : 0.f;
      if (ok) out[(size_t)t * VOC + v] = w;
      float r = wred64(w);
      if ((threadIdx.x & 63) == 0)
        rowp[(size_t)t * NPART + (size_t)blockIdx.x * 4 + wv] = r;
    }
  }
}

__global__ __launch_bounds__(256) void k_rowsum(const float* __restrict__ rowp, float* __restrict__ inv) {
  const int t = blockIdx.x;
  float acc = 0.f;
  for (int i = threadIdx.x; i < NPART; i += 256) acc += rowp[(size_t)t * NPART + i];
  acc = wred64(acc);
  __shared__ float sr[4];
  if ((threadIdx.x & 63) == 0) sr[threadIdx.x >> 6] = acc;
  __syncthreads();
  if (threadIdx.x == 0) inv[t] = 1.f / (sr[0] + sr[1] + sr[2] + sr[3]);
}

__global__ __launch_bounds__(256) void k_scale(float* __restrict__ out, const float* __restrict__ inv) {
  const int t = blockIdx.y;
  const float s = inv[t];
  const size_t base = (size_t)t * VOC;
  const int v0 = blockIdx.x * 2048 + threadIdx.x;
  #pragma unroll
  for (int k = 0; k < 8; ++k) {
    const int v = v0 + k * 256;
    if (v < VOC) out[base + v] *= s;
  }
}

extern "C" void kernel_launch(void* const* d_in, const int* in_sizes, int n_in,
                              void* d_out, int out_size, void* d_ws, size_t ws_size,
                              hipStream_t stream) {
  const int*   dec  = (const int*)  d_in[0];
  const float* enc  = (const float*)d_in[1];
  const float* emb  = (const float*)d_in[2];
  const float* Wax  = (const float*)d_in[3];
  const float* Wac  = (const float*)d_in[4];
  const float* ba   = (const float*)d_in[5];
  const float* va   = (const float*)d_in[6];
  const float* vab  = (const float*)d_in[7];
  const float* Wih0 = (const float*)d_in[8];
  const float* bih0 = (const float*)d_in[9];
  const float* Whh0 = (const float*)d_in[10];
  const float* bhh0 = (const float*)d_in[11];
  const float* Wih1 = (const float*)d_in[12];
  const float* bih1 = (const float*)d_in[13];
  const float* Whh1 = (const float*)d_in[14];
  const float* bhh1 = (const float*)d_in[15];
  const float* Wh   = (const float*)d_in[16];
  const float* bh   = (const float*)d_in[17];
  const float* vh   = (const float*)d_in[18];
  const float* vhb  = (const float*)d_in[19];
  const float* Wf1  = (const float*)d_in[20];
  const float* bf1  = (const float*)d_in[21];
  const float* Wf2  = (const float*)d_in[22];
  const float* bf2  = (const float*)d_in[23];
  float* out = (float*)d_out;
  float* ws  = (float*)d_ws;

  k_init<<<1, 256, 0, stream>>>(ws);

  // Genc[r][s] = Wih0[r, :1024] . enc[s]          (M=3072, N=512)
  k_gemm<<<dim3(8, 48), 256, 0, stream>>>(Wih0, 2048, nullptr, enc, 1024, 0,
                                          nullptr, ws + WS_GENC, 512, G3, S_LEN, 0);
  // gi_tok[t][r] = emb[dec[t]] . Wih0[r, 1024:] + bih0[r]   (M=512, N=3072)
  k_gemm<<<dim3(48, 8), 256, 0, stream>>>(emb, 1024, dec, Wih0, 2048, 1024,
                                          bih0, ws + WS_GITOK, G3, T_LEN, G3, 0);
  // Ex[s][i] = enc[s] . Wa_x[i] + ba[i]           (M=512, N=256)
  k_gemm<<<dim3(4, 8), 256, 0, stream>>>(enc, 1024, nullptr, Wax, 1024, 0,
                                         ba, ws + WS_EX, AD, S_LEN, AD, 0);

  k_recur<<<NWG, NT, 0, stream>>>(ws, Whh0, bhh0, Wih1, bih1, Whh1, bhh1,
                                  Wh, bh, vh, vhb, va, vab, Wac);

  // FC1[t] = relu(Wf1 @ H1[t] + bf1)              (M=512, N=32)
  k_gemm<<<dim3(1, 8), 256, 0, stream>>>(ws + WS_H1, 1024, nullptr, Wf1, 1024, 0,
                                         bf1, ws + WS_FC1, 32, T_LEN, 32, 1);

  k_head<<<197, 256, 0, stream>>>(ws + WS_FC1, Wf2, bf2, out, ws + WS_ROWP);
  k_rowsum<<<512, 256, 0, stream>>>(ws + WS_ROWP, ws + WS_INV);
  k_scale<<<dim3(25, 512), 256, 0, stream>>>(out, ws + WS_INV);
}